// Round 14
// baseline (449.118 us; speedup 1.0000x reference)
//
#include <hip/hip_runtime.h>

#define EDGES 400000
#define DIM 128

typedef __attribute__((ext_vector_type(8))) short bf16x8;
typedef __attribute__((ext_vector_type(4))) float f32x4;

// fp32 -> bf16 round-to-nearest-even (no NaN handling needed here)
__device__ __forceinline__ short f2bf(float f) {
    unsigned u = __builtin_bit_cast(unsigned, f);
    unsigned r = (u + 0x7fffu + ((u >> 16) & 1u)) >> 16;
    return (short)r;
}

// Rearrange W1 [768][384] fp32 -> bf16 frag-major for 16x16x32 MFMA B-operand:
// frag (nt, s): lane holds B[k = (lane>>4)*8 + j][n = lane&15], k-step s, n-tile nt.
// W1f[((nt*12+s)*64+lane)*8 + j] = bf16( W1[(nt*16+(lane&15))*384 + s*32+(lane>>4)*8+j] )
__global__ void prep_w1(const float* __restrict__ W1, short* __restrict__ W1f) {
    int idx = blockIdx.x * 256 + threadIdx.x;       // 294912 = 48*12*64*8
    int j    = idx & 7;
    int lane = (idx >> 3) & 63;
    int fs   = idx >> 9;                            // nt*12 + s
    int s    = fs % 12;
    int nt   = fs / 12;
    int n = nt * 16 + (lane & 15);
    int k = s * 32 + (lane >> 4) * 8 + j;
    W1f[idx] = f2bf(W1[n * 384 + k]);
}

// Block: 256 threads = 4 waves, 128 edges (each wave owns 2 M-tiles of 16 edges).
// Round-13 structure (278us verified: 4 LDS buffers, one barrier per 2 nt) with
// ONE change: __launch_bounds__(256, 3) -> THREE co-resident blocks/CU.
// Evidence: per nt-round a CU's 8 waves issue 96 ds_read_b128 x 12cy = 1152cy
// of LDS work but the measured period is 2279cy -> LDS pipe 50% idle. The idle
// is barrier + vmcnt-drain + epilogue-VALU phases that 2 blocks can't cover
// for each other. 3 blocks fit: LDS 3x48KB=144<=160KB, VGPR 124<=128 (4
// waves/SIMD feasible), and a third block's ds_read burst fills the gaps.
// (History: r10 rotation/setprio regressed; r11 no-LDS regressed 3.5x — LDS is
// the only B-path with enough BW; r1/7/9: >128-VGPR layouts spill, M_w=32 cap.)
__global__ __launch_bounds__(256, 3)
void edge_mlp(const float* __restrict__ x,
              const int*   __restrict__ ei,      // [2][EDGES]
              const float* __restrict__ b1,      // [768]
              const float* __restrict__ W2,      // [768]
              const float* __restrict__ b2p,     // [1]
              const short* __restrict__ W1f,     // frag-major bf16 W1
              float* __restrict__ out)           // [EDGES]
{
    __shared__ short sB[4][12 * 512];            // 4 x 12 frags x 1KB = 48 KB

    const int tid  = threadIdx.x;
    const int lane = tid & 63;
    const int wave = tid >> 6;
    const int m    = lane & 15;                  // A-row / B-col / D-col index
    const int quad = lane >> 4;
    const int eb   = blockIdx.x * 128;

    // ---- async stage nt 0 and 1 (12 frags each; each wave issues 3 per nt) ----
    #pragma unroll
    for (int jj = 0; jj < 3; ++jj) {
        int s = wave * 3 + jj;
        __builtin_amdgcn_global_load_lds(
            (const __attribute__((address_space(1))) void*)(W1f + (s << 9) + lane * 8),
            (__attribute__((address_space(3))) void*)(&sB[0][s << 9]),
            16, 0, 0);
        __builtin_amdgcn_global_load_lds(
            (const __attribute__((address_space(1))) void*)(W1f + 6144 + (s << 9) + lane * 8),
            (__attribute__((address_space(3))) void*)(&sB[1][s << 9]),
            16, 0, 0);
    }

    // ---- build A fragments in registers: 2 M-tiles x 12 K-steps (96 VGPRs) ----
    // A-frag layout (m89/m120-verified): lane holds A[m=lane&15][k=quad*8+j].
    // feat col kc = 32*s + 8*quad + j ; sections: s 0-3 mean, 4-7 prod, 8-11 sqdiff,
    // all three from the SAME x columns -> each x chunk loaded once.
    bf16x8 afrag[2][12];
    #pragma unroll
    for (int T = 0; T < 2; ++T) {
        int e = eb + wave * 32 + T * 16 + m;
        const float* r0 = x + (size_t)ei[e] * DIM;
        const float* r1 = x + (size_t)ei[EDGES + e] * DIM;
        #pragma unroll
        for (int i = 0; i < 4; ++i) {
            int c = i * 32 + quad * 8;
            f32x4 a0 = *(const f32x4*)(r0 + c);
            f32x4 a1 = *(const f32x4*)(r0 + c + 4);
            f32x4 c0 = *(const f32x4*)(r1 + c);
            f32x4 c1 = *(const f32x4*)(r1 + c + 4);
            bf16x8 fm, fp, fd;
            #pragma unroll
            for (int j = 0; j < 4; ++j) {
                float aa = a0[j], bb = c0[j];
                fm[j] = f2bf((aa + bb) * 0.5f);
                fp[j] = f2bf(aa * bb);
                float dd = aa - bb;
                fd[j] = f2bf(dd * dd);
                aa = a1[j]; bb = c1[j];
                fm[j + 4] = f2bf((aa + bb) * 0.5f);
                fp[j + 4] = f2bf(aa * bb);
                dd = aa - bb;
                fd[j + 4] = f2bf(dd * dd);
            }
            afrag[T][i]     = fm;   // mean      -> k in [0,128)
            afrag[T][i + 4] = fp;   // product   -> k in [128,256)
            afrag[T][i + 8] = fd;   // sq. diff  -> k in [256,384)
        }
    }

    float yp0[4] = {0.f, 0.f, 0.f, 0.f};
    float yp1[4] = {0.f, 0.f, 0.f, 0.f};

    __syncthreads();   // waits own global_load_lds (vmcnt) then barrier -> nt 0,1 ready

    for (int p = 0; p < 24; ++p) {
        const int nt0 = 2 * p;

        // prefetch pair (nt0+2, nt0+3) into the buffers read last iteration
        // (safe: post-barrier, all waves finished reading them)
        if (p < 23) {
            const short* srcA = W1f + (size_t)(nt0 + 2) * 6144;
            const short* srcB = W1f + (size_t)(nt0 + 3) * 6144;
            short* dstA = sB[(nt0 + 2) & 3];
            short* dstB = sB[(nt0 + 3) & 3];
            #pragma unroll
            for (int jj = 0; jj < 3; ++jj) {
                int s = wave * 3 + jj;
                __builtin_amdgcn_global_load_lds(
                    (const __attribute__((address_space(1))) void*)(srcA + (s << 9) + lane * 8),
                    (__attribute__((address_space(3))) void*)(dstA + (s << 9)),
                    16, 0, 0);
                __builtin_amdgcn_global_load_lds(
                    (const __attribute__((address_space(1))) void*)(srcB + (s << 9) + lane * 8),
                    (__attribute__((address_space(3))) void*)(dstB + (s << 9)),
                    16, 0, 0);
            }
        }

        // ---- two nt bodies per barrier period (identical to round-0 body) ----
        #pragma unroll
        for (int h = 0; h < 2; ++h) {
            const int nt = nt0 + h;
            f32x4 acc0 = {0.f, 0.f, 0.f, 0.f};
            f32x4 acc1 = {0.f, 0.f, 0.f, 0.f};
            const bf16x8* bp = (const bf16x8*)sB[nt & 3];
            #pragma unroll
            for (int s = 0; s < 12; ++s) {
                bf16x8 bfrag = bp[(s << 6) + lane];   // conflict-free: addr = s*1024 + lane*16
                acc0 = __builtin_amdgcn_mfma_f32_16x16x32_bf16(afrag[0][s], bfrag, acc0, 0, 0, 0);
                acc1 = __builtin_amdgcn_mfma_f32_16x16x32_bf16(afrag[1][s], bfrag, acc1, 0, 0, 0);
            }

            // epilogue: D layout col=lane&15, row=quad*4+r (m89-verified)
            int ng = nt * 16 + m;
            float bias = b1[ng];
            float w2v  = W2[ng];
            #pragma unroll
            for (int r = 0; r < 4; ++r) {
                float h0 = acc0[r] + bias;
                float h1 = acc1[r] + bias;
                yp0[r] = fmaf(fmaxf(h0, 0.f), w2v, yp0[r]);
                yp1[r] = fmaf(fmaxf(h1, 0.f), w2v, yp1[r]);
            }
        }

        __syncthreads();   // prefetch pair drained + all waves done with bufs of this pair
    }

    // reduce the 16 columns held across lanes of each quad-group
    #pragma unroll
    for (int off = 8; off >= 1; off >>= 1) {
        #pragma unroll
        for (int r = 0; r < 4; ++r) {
            yp0[r] += __shfl_xor(yp0[r], off, 64);
            yp1[r] += __shfl_xor(yp1[r], off, 64);
        }
    }
    if (m == 0) {
        float b2v = b2p[0];
        int e0 = eb + wave * 32 + quad * 4;
        #pragma unroll
        for (int r = 0; r < 4; ++r) {
            out[e0 + r]      = yp0[r] + b2v;
            out[e0 + 16 + r] = yp1[r] + b2v;
        }
    }
}

extern "C" void kernel_launch(void* const* d_in, const int* in_sizes, int n_in,
                              void* d_out, int out_size, void* d_ws, size_t ws_size,
                              hipStream_t stream) {
    const float* x  = (const float*)d_in[0];
    const int*   ei = (const int*)  d_in[1];
    // d_in[2]=edge_attr3, d_in[3]=edge_attr4, d_in[4]=batch : unused by reference
    const float* W1 = (const float*)d_in[5];
    const float* b1 = (const float*)d_in[6];
    const float* W2 = (const float*)d_in[7];
    const float* b2 = (const float*)d_in[8];
    short* W1f = (short*)d_ws;                 // 589824 B frag-major bf16 W1
    float* out = (float*)d_out;

    prep_w1<<<1152, 256, 0, stream>>>(W1, W1f);            // 294912 elems
    edge_mlp<<<3125, 256, 0, stream>>>(x, ei, b1, W2, b2, W1f, out);
}

// Round 15
// 372.152 us; speedup vs baseline: 1.2068x; 1.2068x over previous
//
#include <hip/hip_runtime.h>

#define EDGES 400000
#define DIM 128

typedef __attribute__((ext_vector_type(8))) short bf16x8;
typedef __attribute__((ext_vector_type(4))) float f32x4;

// fp32 -> bf16 round-to-nearest-even (no NaN handling needed here)
__device__ __forceinline__ short f2bf(float f) {
    unsigned u = __builtin_bit_cast(unsigned, f);
    unsigned r = (u + 0x7fffu + ((u >> 16) & 1u)) >> 16;
    return (short)r;
}

// Rearrange W1 [768][384] fp32 -> bf16 frag-major for 16x16x32 MFMA B-operand:
// frag (nt, s): lane holds B[k = (lane>>4)*8 + j][n = lane&15], k-step s, n-tile nt.
// W1f[((nt*12+s)*64+lane)*8 + j] = bf16( W1[(nt*16+(lane&15))*384 + s*32+(lane>>4)*8+j] )
__global__ void prep_w1(const float* __restrict__ W1, short* __restrict__ W1f) {
    int idx = blockIdx.x * 256 + threadIdx.x;       // 294912 = 48*12*64*8
    int j    = idx & 7;
    int lane = (idx >> 3) & 63;
    int fs   = idx >> 9;                            // nt*12 + s
    int s    = fs % 12;
    int nt   = fs / 12;
    int n = nt * 16 + (lane & 15);
    int k = s * 32 + (lane >> 4) * 8 + j;
    W1f[idx] = f2bf(W1[n * 384 + k]);
}

// Block: 512 threads = 8 waves, 256 edges (each wave owns 2 M-tiles of 16 edges).
// Same per-wave structure + 4-buffer/barrier-per-2-nt schedule as the 278us r13
// kernel; ONE change: 8-wave blocks -> 2 resident blocks/CU = 16 waves/CU
// (vs ~8) for latency hiding. Rationale: r13 pipe sums (LDS ~132us, MFMA
// ~114us, VALU ~78us vs 278us measured) show no pipe >47% busy -> the kernel
// is latency/dependency-bound, so more waves is the lever.
// REGISTER RULE (r1/r13/r14 measured): the allocator targets 2x the declared
// min-waves-per-EU: (128,2)->128cap, (256,2)->124 ok, (256,3)->85 SPILL.
// Therefore __launch_bounds__(512, 2): min=2 -> target 4 waves/EU -> 128-VGPR
// cap, which the 96-reg afrag + acc + yp (~124) fits. 16 waves/CU at 124 VGPR
// is exactly 4 waves/SIMD = the HW limit at this register count.
// (History: r10 rotation/setprio regressed; r11 no-LDS 3.5x regression;
// r1/7/9/14: any layout needing >128 VGPRs spills, M_w=32 is the wall.)
__global__ __launch_bounds__(512, 2)
void edge_mlp(const float* __restrict__ x,
              const int*   __restrict__ ei,      // [2][EDGES]
              const float* __restrict__ b1,      // [768]
              const float* __restrict__ W2,      // [768]
              const float* __restrict__ b2p,     // [1]
              const short* __restrict__ W1f,     // frag-major bf16 W1
              float* __restrict__ out)           // [EDGES]
{
    __shared__ short sB[4][12 * 512];            // 4 x 12 frags x 1KB = 48 KB

    const int tid  = threadIdx.x;
    const int lane = tid & 63;
    const int wave = tid >> 6;                   // 0..7
    const int m    = lane & 15;                  // A-row / B-col / D-col index
    const int quad = lane >> 4;
    const int eb   = blockIdx.x * 256;
    const int sw   = wave & 3;                   // staging sub-index within nt
    const int whi  = wave >> 2;                  // 0: stages ntA, 1: stages ntB

    // ---- async stage nt 0 (waves 0-3) and nt 1 (waves 4-7): 3 frags each ----
    {
        const short* src = W1f + (size_t)whi * 6144;
        short* dst = sB[whi];
        #pragma unroll
        for (int jj = 0; jj < 3; ++jj) {
            int s = sw * 3 + jj;
            __builtin_amdgcn_global_load_lds(
                (const __attribute__((address_space(1))) void*)(src + (s << 9) + lane * 8),
                (__attribute__((address_space(3))) void*)(dst + (s << 9)),
                16, 0, 0);
        }
    }

    // ---- build A fragments in registers: 2 M-tiles x 12 K-steps (96 VGPRs) ----
    // A-frag layout (m89/m120-verified): lane holds A[m=lane&15][k=quad*8+j].
    // feat col kc = 32*s + 8*quad + j ; sections: s 0-3 mean, 4-7 prod, 8-11 sqdiff,
    // all three from the SAME x columns -> each x chunk loaded once.
    // Tail block (grid 1563 covers 400128 >= 400000): clamp load index, guard store.
    bf16x8 afrag[2][12];
    #pragma unroll
    for (int T = 0; T < 2; ++T) {
        int e = eb + wave * 32 + T * 16 + m;
        e = e < EDGES ? e : (EDGES - 1);
        const float* r0 = x + (size_t)ei[e] * DIM;
        const float* r1 = x + (size_t)ei[EDGES + e] * DIM;
        #pragma unroll
        for (int i = 0; i < 4; ++i) {
            int c = i * 32 + quad * 8;
            f32x4 a0 = *(const f32x4*)(r0 + c);
            f32x4 a1 = *(const f32x4*)(r0 + c + 4);
            f32x4 c0 = *(const f32x4*)(r1 + c);
            f32x4 c1 = *(const f32x4*)(r1 + c + 4);
            bf16x8 fm, fp, fd;
            #pragma unroll
            for (int j = 0; j < 4; ++j) {
                float aa = a0[j], bb = c0[j];
                fm[j] = f2bf((aa + bb) * 0.5f);
                fp[j] = f2bf(aa * bb);
                float dd = aa - bb;
                fd[j] = f2bf(dd * dd);
                aa = a1[j]; bb = c1[j];
                fm[j + 4] = f2bf((aa + bb) * 0.5f);
                fp[j + 4] = f2bf(aa * bb);
                dd = aa - bb;
                fd[j + 4] = f2bf(dd * dd);
            }
            afrag[T][i]     = fm;   // mean      -> k in [0,128)
            afrag[T][i + 4] = fp;   // product   -> k in [128,256)
            afrag[T][i + 8] = fd;   // sq. diff  -> k in [256,384)
        }
    }

    float yp0[4] = {0.f, 0.f, 0.f, 0.f};
    float yp1[4] = {0.f, 0.f, 0.f, 0.f};

    __syncthreads();   // waits own global_load_lds (vmcnt) then barrier -> nt 0,1 ready

    for (int p = 0; p < 24; ++p) {
        const int nt0 = 2 * p;

        // prefetch pair (nt0+2, nt0+3): waves 0-3 stage the first, 4-7 the second
        // (safe: post-barrier, all waves finished reading those buffers)
        if (p < 23) {
            const int ntp = nt0 + 2 + whi;
            const short* src = W1f + (size_t)ntp * 6144;
            short* dst = sB[ntp & 3];
            #pragma unroll
            for (int jj = 0; jj < 3; ++jj) {
                int s = sw * 3 + jj;
                __builtin_amdgcn_global_load_lds(
                    (const __attribute__((address_space(1))) void*)(src + (s << 9) + lane * 8),
                    (__attribute__((address_space(3))) void*)(dst + (s << 9)),
                    16, 0, 0);
            }
        }

        // ---- two nt bodies per barrier period (identical to r13 body) ----
        #pragma unroll
        for (int h = 0; h < 2; ++h) {
            const int nt = nt0 + h;
            f32x4 acc0 = {0.f, 0.f, 0.f, 0.f};
            f32x4 acc1 = {0.f, 0.f, 0.f, 0.f};
            const bf16x8* bp = (const bf16x8*)sB[nt & 3];
            #pragma unroll
            for (int s = 0; s < 12; ++s) {
                bf16x8 bfrag = bp[(s << 6) + lane];   // conflict-free: addr = s*1024 + lane*16
                acc0 = __builtin_amdgcn_mfma_f32_16x16x32_bf16(afrag[0][s], bfrag, acc0, 0, 0, 0);
                acc1 = __builtin_amdgcn_mfma_f32_16x16x32_bf16(afrag[1][s], bfrag, acc1, 0, 0, 0);
            }

            // epilogue: D layout col=lane&15, row=quad*4+r (m89-verified)
            int ng = nt * 16 + m;
            float bias = b1[ng];
            float w2v  = W2[ng];
            #pragma unroll
            for (int r = 0; r < 4; ++r) {
                float h0 = acc0[r] + bias;
                float h1 = acc1[r] + bias;
                yp0[r] = fmaf(fmaxf(h0, 0.f), w2v, yp0[r]);
                yp1[r] = fmaf(fmaxf(h1, 0.f), w2v, yp1[r]);
            }
        }

        __syncthreads();   // prefetch pair drained + all waves done with bufs of this pair
    }

    // reduce the 16 columns held across lanes of each quad-group
    #pragma unroll
    for (int off = 8; off >= 1; off >>= 1) {
        #pragma unroll
        for (int r = 0; r < 4; ++r) {
            yp0[r] += __shfl_xor(yp0[r], off, 64);
            yp1[r] += __shfl_xor(yp1[r], off, 64);
        }
    }
    if (m == 0) {
        float b2v = b2p[0];
        int e0 = eb + wave * 32 + quad * 4;
        #pragma unroll
        for (int r = 0; r < 4; ++r) {
            if (e0 + r < EDGES)      out[e0 + r]      = yp0[r] + b2v;
            if (e0 + 16 + r < EDGES) out[e0 + 16 + r] = yp1[r] + b2v;
        }
    }
}

extern "C" void kernel_launch(void* const* d_in, const int* in_sizes, int n_in,
                              void* d_out, int out_size, void* d_ws, size_t ws_size,
                              hipStream_t stream) {
    const float* x  = (const float*)d_in[0];
    const int*   ei = (const int*)  d_in[1];
    // d_in[2]=edge_attr3, d_in[3]=edge_attr4, d_in[4]=batch : unused by reference
    const float* W1 = (const float*)d_in[5];
    const float* b1 = (const float*)d_in[6];
    const float* W2 = (const float*)d_in[7];
    const float* b2 = (const float*)d_in[8];
    short* W1f = (short*)d_ws;                 // 589824 B frag-major bf16 W1
    float* out = (float*)d_out;

    prep_w1<<<1152, 256, 0, stream>>>(W1, W1f);            // 294912 elems
    edge_mlp<<<1563, 512, 0, stream>>>(x, ei, b1, W2, b2, W1f, out);   // 1563*256 = 400128 edges
}

// Round 16
// 361.424 us; speedup vs baseline: 1.2426x; 1.0297x over previous
//
#include <hip/hip_runtime.h>

#define EDGES 400000
#define DIM 128

typedef __attribute__((ext_vector_type(8))) short bf16x8;
typedef __attribute__((ext_vector_type(4))) float f32x4;

// fp32 -> bf16 round-to-nearest-even (no NaN handling needed here)
__device__ __forceinline__ short f2bf(float f) {
    unsigned u = __builtin_bit_cast(unsigned, f);
    unsigned r = (u + 0x7fffu + ((u >> 16) & 1u)) >> 16;
    return (short)r;
}

// Rearrange W1 [768][384] fp32 -> bf16 frag-major for 16x16x32 MFMA B-operand:
// frag (nt, s): lane holds B[k = (lane>>4)*8 + j][n = lane&15], k-step s, n-tile nt.
// W1f[((nt*12+s)*64+lane)*8 + j] = bf16( W1[(nt*16+(lane&15))*384 + s*32+(lane>>4)*8+j] )
__global__ void prep_w1(const float* __restrict__ W1, short* __restrict__ W1f) {
    int idx = blockIdx.x * 256 + threadIdx.x;       // 294912 = 48*12*64*8
    int j    = idx & 7;
    int lane = (idx >> 3) & 63;
    int fs   = idx >> 9;                            // nt*12 + s
    int s    = fs % 12;
    int nt   = fs / 12;
    int n = nt * 16 + (lane & 15);
    int k = s * 32 + (lane >> 4) * 8 + j;
    W1f[idx] = f2bf(W1[n * 384 + k]);
}

// Block: 256 threads = 4 waves, 128 edges (each wave owns 2 M-tiles of 16 edges).
// r13 structure (278us verified: 4 LDS buffers, one barrier per 2 nt) with ONE
// change: EXPLICIT 2-deep bfrag pipeline in the s-loop (named bcur/bnext).
// Evidence: r13's VGPR_Count=124/128 leaves room for exactly ONE 4-reg bfrag
// in flight -> every K-step exposes ~120cy of ds_read latency (m117), giving
// ~1560cy/nt/wave vs 233cy of MFMA; measured 2279cy/nt matches d=1 latency
// exposure, and retro-explains r11's 3.5x blowup (global path, d~1, 200+cy).
// bcur/bnext issues the s+1 read before the s MFMAs -> d=2, halving exposure.
// 124+4 = 128 fits the proven register cap exactly.
// (History: r10 rotation/setprio regressed; r11 no-LDS 3.5x; r14 3-blocks ->
// spill (allocator targets 2x min-waves/EU); r15 8-wave blocks -> occupancy
// did NOT rise, dur 304; >128-VGPR layouts always spill -> M_w=32 wall.)
__global__ __launch_bounds__(256, 2)
void edge_mlp(const float* __restrict__ x,
              const int*   __restrict__ ei,      // [2][EDGES]
              const float* __restrict__ b1,      // [768]
              const float* __restrict__ W2,      // [768]
              const float* __restrict__ b2p,     // [1]
              const short* __restrict__ W1f,     // frag-major bf16 W1
              float* __restrict__ out)           // [EDGES]
{
    __shared__ short sB[4][12 * 512];            // 4 x 12 frags x 1KB = 48 KB

    const int tid  = threadIdx.x;
    const int lane = tid & 63;
    const int wave = tid >> 6;
    const int m    = lane & 15;                  // A-row / B-col / D-col index
    const int quad = lane >> 4;
    const int eb   = blockIdx.x * 128;

    // ---- async stage nt 0 and 1 (12 frags each; each wave issues 3 per nt) ----
    #pragma unroll
    for (int jj = 0; jj < 3; ++jj) {
        int s = wave * 3 + jj;
        __builtin_amdgcn_global_load_lds(
            (const __attribute__((address_space(1))) void*)(W1f + (s << 9) + lane * 8),
            (__attribute__((address_space(3))) void*)(&sB[0][s << 9]),
            16, 0, 0);
        __builtin_amdgcn_global_load_lds(
            (const __attribute__((address_space(1))) void*)(W1f + 6144 + (s << 9) + lane * 8),
            (__attribute__((address_space(3))) void*)(&sB[1][s << 9]),
            16, 0, 0);
    }

    // ---- build A fragments in registers: 2 M-tiles x 12 K-steps (96 VGPRs) ----
    // A-frag layout (m89/m120-verified): lane holds A[m=lane&15][k=quad*8+j].
    // feat col kc = 32*s + 8*quad + j ; sections: s 0-3 mean, 4-7 prod, 8-11 sqdiff,
    // all three from the SAME x columns -> each x chunk loaded once.
    bf16x8 afrag[2][12];
    #pragma unroll
    for (int T = 0; T < 2; ++T) {
        int e = eb + wave * 32 + T * 16 + m;
        const float* r0 = x + (size_t)ei[e] * DIM;
        const float* r1 = x + (size_t)ei[EDGES + e] * DIM;
        #pragma unroll
        for (int i = 0; i < 4; ++i) {
            int c = i * 32 + quad * 8;
            f32x4 a0 = *(const f32x4*)(r0 + c);
            f32x4 a1 = *(const f32x4*)(r0 + c + 4);
            f32x4 c0 = *(const f32x4*)(r1 + c);
            f32x4 c1 = *(const f32x4*)(r1 + c + 4);
            bf16x8 fm, fp, fd;
            #pragma unroll
            for (int j = 0; j < 4; ++j) {
                float aa = a0[j], bb = c0[j];
                fm[j] = f2bf((aa + bb) * 0.5f);
                fp[j] = f2bf(aa * bb);
                float dd = aa - bb;
                fd[j] = f2bf(dd * dd);
                aa = a1[j]; bb = c1[j];
                fm[j + 4] = f2bf((aa + bb) * 0.5f);
                fp[j + 4] = f2bf(aa * bb);
                dd = aa - bb;
                fd[j + 4] = f2bf(dd * dd);
            }
            afrag[T][i]     = fm;   // mean      -> k in [0,128)
            afrag[T][i + 4] = fp;   // product   -> k in [128,256)
            afrag[T][i + 8] = fd;   // sq. diff  -> k in [256,384)
        }
    }

    float yp0[4] = {0.f, 0.f, 0.f, 0.f};
    float yp1[4] = {0.f, 0.f, 0.f, 0.f};

    __syncthreads();   // waits own global_load_lds (vmcnt) then barrier -> nt 0,1 ready

    for (int p = 0; p < 24; ++p) {
        const int nt0 = 2 * p;

        // prefetch pair (nt0+2, nt0+3) into the buffers read last iteration
        // (safe: post-barrier, all waves finished reading them)
        if (p < 23) {
            const short* srcA = W1f + (size_t)(nt0 + 2) * 6144;
            const short* srcB = W1f + (size_t)(nt0 + 3) * 6144;
            short* dstA = sB[(nt0 + 2) & 3];
            short* dstB = sB[(nt0 + 3) & 3];
            #pragma unroll
            for (int jj = 0; jj < 3; ++jj) {
                int s = wave * 3 + jj;
                __builtin_amdgcn_global_load_lds(
                    (const __attribute__((address_space(1))) void*)(srcA + (s << 9) + lane * 8),
                    (__attribute__((address_space(3))) void*)(dstA + (s << 9)),
                    16, 0, 0);
                __builtin_amdgcn_global_load_lds(
                    (const __attribute__((address_space(1))) void*)(srcB + (s << 9) + lane * 8),
                    (__attribute__((address_space(3))) void*)(dstB + (s << 9)),
                    16, 0, 0);
            }
        }

        // ---- two nt bodies per barrier period; s-loop explicitly 2-deep ----
        #pragma unroll
        for (int h = 0; h < 2; ++h) {
            const int nt = nt0 + h;
            f32x4 acc0 = {0.f, 0.f, 0.f, 0.f};
            f32x4 acc1 = {0.f, 0.f, 0.f, 0.f};
            const bf16x8* bp = (const bf16x8*)sB[nt & 3];
            bf16x8 bcur = bp[lane];                       // s = 0
            #pragma unroll
            for (int s = 0; s < 12; ++s) {
                // issue s+1 read BEFORE the s MFMAs (independent -> d=2 pipeline)
                bf16x8 bnext = bp[(((s + 1) & 15) << 6) + lane];  // s=11: dummy (idx 12*64, within 48KB buf? no)
                if (s == 11) bnext = bcur;                 // keep defined, no OOB use
                acc0 = __builtin_amdgcn_mfma_f32_16x16x32_bf16(afrag[0][s], bcur, acc0, 0, 0, 0);
                acc1 = __builtin_amdgcn_mfma_f32_16x16x32_bf16(afrag[1][s], bcur, acc1, 0, 0, 0);
                bcur = bnext;
            }

            // epilogue: D layout col=lane&15, row=quad*4+r (m89-verified)
            int ng = nt * 16 + m;
            float bias = b1[ng];
            float w2v  = W2[ng];
            #pragma unroll
            for (int r = 0; r < 4; ++r) {
                float h0 = acc0[r] + bias;
                float h1 = acc1[r] + bias;
                yp0[r] = fmaf(fmaxf(h0, 0.f), w2v, yp0[r]);
                yp1[r] = fmaf(fmaxf(h1, 0.f), w2v, yp1[r]);
            }
        }

        __syncthreads();   // prefetch pair drained + all waves done with bufs of this pair
    }

    // reduce the 16 columns held across lanes of each quad-group
    #pragma unroll
    for (int off = 8; off >= 1; off >>= 1) {
        #pragma unroll
        for (int r = 0; r < 4; ++r) {
            yp0[r] += __shfl_xor(yp0[r], off, 64);
            yp1[r] += __shfl_xor(yp1[r], off, 64);
        }
    }
    if (m == 0) {
        float b2v = b2p[0];
        int e0 = eb + wave * 32 + quad * 4;
        #pragma unroll
        for (int r = 0; r < 4; ++r) {
            out[e0 + r]      = yp0[r] + b2v;
            out[e0 + 16 + r] = yp1[r] + b2v;
        }
    }
}

extern "C" void kernel_launch(void* const* d_in, const int* in_sizes, int n_in,
                              void* d_out, int out_size, void* d_ws, size_t ws_size,
                              hipStream_t stream) {
    const float* x  = (const float*)d_in[0];
    const int*   ei = (const int*)  d_in[1];
    // d_in[2]=edge_attr3, d_in[3]=edge_attr4, d_in[4]=batch : unused by reference
    const float* W1 = (const float*)d_in[5];
    const float* b1 = (const float*)d_in[6];
    const float* W2 = (const float*)d_in[7];
    const float* b2 = (const float*)d_in[8];
    short* W1f = (short*)d_ws;                 // 589824 B frag-major bf16 W1
    float* out = (float*)d_out;

    prep_w1<<<1152, 256, 0, stream>>>(W1, W1f);            // 294912 elems
    edge_mlp<<<3125, 256, 0, stream>>>(x, ei, b1, W2, b2, W1f, out);
}